// Round 16
// baseline (216.471 us; speedup 1.0000x reference)
//
#include <hip/hip_runtime.h>
#include <math.h>

#define B_   4
#define C_   256
#define G_   32
#define CPG  8                 // channels per group
#define N_   4096              // H*W
#define NPG  (CPG * N_)        // 32768 elements per group
#define EPS  1e-5f
#define SCALE 0.0625f          // C^-0.5 = 1/16
#define NCH  32                // key chunks of 64 per (split) half
#define QKVW_ELEMS 196608      // 3C x C
#define OUTW_ELEMS 65536       // C x C

typedef __attribute__((ext_vector_type(8)))  __bf16 bf16x8;
typedef __attribute__((ext_vector_type(4)))  __bf16 bf16x4;
typedef __attribute__((ext_vector_type(16))) float  f32x16;

__device__ __forceinline__ void stage16(const __bf16* g, __bf16* l) {
    __builtin_amdgcn_global_load_lds(
        (const __attribute__((address_space(1))) unsigned int*)g,
        (__attribute__((address_space(3))) unsigned int*)l, 16, 0, 0);
}

// ---------------------------------------------------------------------------
// Kernel 1a (verbatim R15, ran): GroupNorm partial sums (blocks 0..511)
// + weight bf16 pre-conversion side-job (blocks 512..639).
// ---------------------------------------------------------------------------
__global__ __launch_bounds__(256) void gn_stats_kernel(const float* __restrict__ x,
                                                       float* __restrict__ part,
                                                       const float* __restrict__ qw,
                                                       const float* __restrict__ ow,
                                                       __bf16* __restrict__ wqb,
                                                       __bf16* __restrict__ wob) {
    int bid = blockIdx.x;
    if (bid >= 512) {
        int et = (bid - 512) * 256 + threadIdx.x;   // 0..32767
        int e8 = et * 8;
        const float* src;
        __bf16* dst;
        if (e8 < QKVW_ELEMS) { src = qw + e8; dst = wqb + e8; }
        else { src = ow + (e8 - QKVW_ELEMS); dst = wob + (e8 - QKVW_ELEMS); }
        float4 t0 = *(const float4*)src;
        float4 t1 = *(const float4*)(src + 4);
        bf16x8 f;
        f[0] = (__bf16)t0.x; f[1] = (__bf16)t0.y; f[2] = (__bf16)t0.z; f[3] = (__bf16)t0.w;
        f[4] = (__bf16)t1.x; f[5] = (__bf16)t1.y; f[6] = (__bf16)t1.z; f[7] = (__bf16)t1.w;
        *(bf16x8*)dst = f;
        return;
    }
    int bg = bid >> 2, seg = bid & 3;
    const float4* xp4 = (const float4*)(x + (size_t)bg * NPG) + seg * 2048;
    int tid = threadIdx.x;

    float s = 0.f, ss = 0.f;
    for (int i = tid; i < 2048; i += 256) {
        float4 t = xp4[i];
        s  += t.x + t.y + t.z + t.w;
        ss += t.x * t.x + t.y * t.y + t.z * t.z + t.w * t.w;
    }
    #pragma unroll
    for (int off = 32; off; off >>= 1) {
        s  += __shfl_xor(s, off, 64);
        ss += __shfl_xor(ss, off, 64);
    }
    __shared__ float rs[2][4];
    int wave = tid >> 6, lane = tid & 63;
    if (lane == 0) { rs[0][wave] = s; rs[1][wave] = ss; }
    __syncthreads();
    if (tid == 0) {
        part[bid * 2]     = rs[0][0] + rs[0][1] + rs[0][2] + rs[0][3];
        part[bid * 2 + 1] = rs[1][0] + rs[1][1] + rs[1][2] + rs[1][3];
    }
}

// ---------------------------------------------------------------------------
// Kernel 1b (verbatim R15, ran): GroupNorm apply, float4-vectorized. Grid 512.
// ---------------------------------------------------------------------------
__global__ __launch_bounds__(256) void gn_apply_kernel(const float* __restrict__ x,
                                                       const float* __restrict__ w,
                                                       const float* __restrict__ bia,
                                                       const float* __restrict__ part,
                                                       __bf16* __restrict__ xnb) {
    int bid = blockIdx.x;                      // 0..511
    int b   = (bid & 7) >> 1;
    int u   = ((bid >> 3) << 1) | (bid & 1);   // 0..127
    int g   = u >> 2;
    int seg = u & 3;
    int bg  = b * 32 + g;
    float s  = part[(bg * 4 + 0) * 2] + part[(bg * 4 + 1) * 2]
             + part[(bg * 4 + 2) * 2] + part[(bg * 4 + 3) * 2];
    float ss = part[(bg * 4 + 0) * 2 + 1] + part[(bg * 4 + 1) * 2 + 1]
             + part[(bg * 4 + 2) * 2 + 1] + part[(bg * 4 + 3) * 2 + 1];
    float mean = s / (float)NPG;
    float var  = ss / (float)NPG - mean * mean;
    float rstd = rsqrtf(var + EPS);

    const float* xp = x + (size_t)bg * NPG;
    int n0 = seg * 1024 + threadIdx.x * 4;

    float4 t[8];
    #pragma unroll
    for (int cc = 0; cc < 8; cc++)
        t[cc] = *(const float4*)(xp + (size_t)cc * N_ + n0);

    float sc[8], sh[8];
    #pragma unroll
    for (int cc = 0; cc < 8; cc++) {
        sc[cc] = rstd * w[g * CPG + cc];
        sh[cc] = bia[g * CPG + cc] - mean * sc[cc];
    }

    size_t base = ((((size_t)(b * 128 + (n0 >> 5)) * 16 + (g >> 1)) * 2 + (g & 1))
                   * 32 + (n0 & 31)) * 8;
    #pragma unroll
    for (int j = 0; j < 4; j++) {
        bf16x8 pk;
        #pragma unroll
        for (int cc = 0; cc < 8; cc++) {
            float tv = ((const float*)&t[cc])[j];
            pk[cc] = (__bf16)(tv * sc[cc] + sh[cc]);
        }
        *(bf16x8*)(xnb + base + j * 8) = pk;
    }
}

// ---------------------------------------------------------------------------
// Kernel 2 (verbatim R15, ran — fp32 W): QKV projection, LDS double-buffered
// x-tiles, grid 768, 4 tiles x 1 ot per block.
// ---------------------------------------------------------------------------
__global__ __launch_bounds__(256) void qkv_kernel(const __bf16* __restrict__ xnb,
                                                  const float* __restrict__ W,
                                                  const float* __restrict__ bias,
                                                  __bf16* __restrict__ q,
                                                  __bf16* __restrict__ k,
                                                  __bf16* __restrict__ v) {
    __shared__ __align__(16) __bf16 x_lds[2][8192];   // 2 x 16 KB
    int bid = blockIdx.x;
    int b   = (bid & 7) >> 1;
    int t2  = ((bid >> 3) << 1) | (bid & 1);   // 0..191
    int ot  = t2 >> 5;
    int nc  = t2 & 31;
    int tid = threadIdx.x, wv = tid >> 6, lane = tid & 63;
    int n31 = lane & 31, q2 = lane >> 5;
    int B0 = ot * 128 + wv * 32;

    bf16x8 wf[16];
    const float* wp = W + (size_t)(B0 + n31) * C_;
    #pragma unroll
    for (int ks = 0; ks < 16; ks++) {
        float4 t0 = *(const float4*)(wp + ks * 16 + q2 * 8);
        float4 t1 = *(const float4*)(wp + ks * 16 + q2 * 8 + 4);
        bf16x8 f;
        f[0] = (__bf16)t0.x; f[1] = (__bf16)t0.y; f[2] = (__bf16)t0.z; f[3] = (__bf16)t0.w;
        f[4] = (__bf16)t1.x; f[5] = (__bf16)t1.y; f[6] = (__bf16)t1.z; f[7] = (__bf16)t1.w;
        wf[ks] = f;
    }

    float bv[16], bvv = 0.f;
    if (ot < 4) {
        #pragma unroll
        for (int gI = 0; gI < 4; gI++)
            #pragma unroll
            for (int j = 0; j < 4; j++)
                bv[gI * 4 + j] = bias[B0 + gI * 8 + 4 * q2 + j];
    } else {
        bvv = bias[B0 + n31];
    }

    const __bf16* xb = xnb + (size_t)b * 128 * 8192;
    const __bf16* xgs = xb + (size_t)(nc * 4) * 8192 + wv * 2048 + lane * 8;

    {   // prologue: stage tile 0
        __bf16* l = (__bf16*)x_lds[0] + wv * 2048;
        #pragma unroll
        for (int i = 0; i < 4; i++)
            stage16(xgs + i * 512, l + i * 512);
    }

    for (int t = 0; t < 4; t++) {
        __syncthreads();                      // tile t staged
        if (t < 3) {                          // stage tile t+1
            const __bf16* g_ = xgs + (size_t)(t + 1) * 8192;
            __bf16* l = (__bf16*)x_lds[(t + 1) & 1] + wv * 2048;
            #pragma unroll
            for (int i = 0; i < 4; i++)
                stage16(g_ + i * 512, l + i * 512);
        }
        int nt = nc * 4 + t;
        const __bf16* xl = (const __bf16*)x_lds[t & 1] + q2 * 256 + n31 * 8;
        bf16x8 xf[16];
        #pragma unroll
        for (int ks = 0; ks < 16; ks++) xf[ks] = *(const bf16x8*)(xl + ks * 512);

        f32x16 acc;
        #pragma unroll
        for (int i = 0; i < 16; i++) acc[i] = 0.f;
        if (ot < 4) {
            #pragma unroll
            for (int ks = 0; ks < 16; ks++)
                acc = __builtin_amdgcn_mfma_f32_32x32x16_bf16(wf[ks], xf[ks], acc, 0, 0, 0);
        } else {
            #pragma unroll
            for (int ks = 0; ks < 16; ks++)
                acc = __builtin_amdgcn_mfma_f32_32x32x16_bf16(xf[ks], wf[ks], acc, 0, 0, 0);
        }

        if (ot < 4) {
            int ocb = (ot < 2) ? B0 : (B0 - 256);
            __bf16* dst = (ot < 2) ? q : k;
            bool isq = (ot < 2);
            #pragma unroll
            for (int gI = 0; gI < 4; gI++) {
                bf16x4 pk;
                #pragma unroll
                for (int j = 0; j < 4; j++) {
                    float y = acc[gI * 4 + j] + bv[gI * 4 + j];
                    if (isq) y *= SCALE;
                    pk[j] = (__bf16)y;
                }
                size_t idx = ((((size_t)(b * 128 + nt) * 16 + ((ocb >> 4) + (gI >> 1))) * 2
                               + (gI & 1)) * 32 + n31) * 8 + 4 * q2;
                *(bf16x4*)(dst + idx) = pk;
            }
        } else {
            int ocb = B0 - 512;
            #pragma unroll
            for (int gI = 0; gI < 4; gI++) {
                bf16x4 pk;
                #pragma unroll
                for (int j = 0; j < 4; j++)
                    pk[j] = (__bf16)(acc[gI * 4 + j] + bvv);
                size_t idx = (((((size_t)(b * 128 + nt) * 2 + (gI >> 1)) * 2 + (gI & 1)) * 8
                               + (ocb >> 5)) * 32 + n31) * 8 + 4 * q2;
                *(bf16x4*)(v + idx) = pk;
            }
        }
    }
}

// ---------------------------------------------------------------------------
// Kernel 3 (R16): attn = R15 with ONE change: producer S-compute split into
// FOUR 4-deep MFMA chains (sa..sd) instead of two 8-deep — dependent-chain
// latency (4x~18 cyc) now fully hidden under issue (16x8 cyc). Producer
// accumulator regs 32 -> 64 (combined 128 = consumer budget; occupancy
// unchanged). Merge sa+sb+sc+sd at exp time. All else byte-identical.
// ---------------------------------------------------------------------------
__global__ __launch_bounds__(512, 4) void attn_kernel(const __bf16* __restrict__ q,
                                                      const __bf16* __restrict__ k,
                                                      const __bf16* __restrict__ v,
                                                      __bf16* __restrict__ aob,
                                                      float* __restrict__ lpart,
                                                      float* __restrict__ ltmp) {
    __shared__ __align__(16) __bf16 k_lds[2][16384];   // 2 x 32 KB double buffer
    __shared__ __align__(16) __bf16 p_lds[2][64 * 64]; // 2 x 8 KB, XOR-swizzled

    int bid   = blockIdx.x;
    int xcd   = bid & 7;
    int b     = xcd >> 1;
    int split = xcd & 1;
    int qt    = bid >> 3;                    // 0..63, 64-row q tile
    int n0    = qt * 64;

    int tid = threadIdx.x;
    int wid = tid >> 6, lane = tid & 63;
    int n31 = lane & 31, q2 = lane >> 5;

    const size_t BSTR = (size_t)N_ * C_;
    const size_t PLANE = (size_t)B_ * C_ * N_;   // elements per split plane
    float* lt = ltmp + (size_t)bid * 128;        // [kt][64] per-block scratch
    const __bf16* kgbase = k + (size_t)(b * 128 + split * 64) * 8192
                           + wid * 2048 + lane * 8;

    // prologue: stage chunk 0 into buf 0 (each wave: 4 x 1 KB segments)
    {
        __bf16* l = (__bf16*)k_lds[0] + wid * 2048;
        #pragma unroll
        for (int i = 0; i < 4; i++)
            stage16(kgbase + i * 512, l + i * 512);
    }

    if (wid < 4) {
        // ================= PRODUCER =================
        int kt = wid & 1;                    // 32-key slice within chunk
        int rt = wid >> 1;                   // 32-row tile within 64 rows
        const __bf16* qg = q + (size_t)(b * 128 + qt * 2 + rt) * 8192
                           + q2 * 256 + n31 * 8;
        bf16x8 qf[16];
        #pragma unroll
        for (int ks = 0; ks < 16; ks++) qf[ks] = *(const bf16x8*)(qg + ks * 512);

        float l_acc = 0.f;
        int prow = rt * 32 + n31;
        int swz  = (prow & 7) << 4;
        int klo  = kt * 8192 + q2 * 256 + n31 * 8;

        for (int ch = 0; ch < NCH; ch++) {
            __syncthreads();                 // K[ch] staged, P[(ch-1)] consumed
            if (ch < NCH - 1) {              // stage K[ch+1] into other buffer
                const __bf16* g = kgbase + (size_t)(ch + 1) * 16384;
                __bf16* l = (__bf16*)k_lds[(ch + 1) & 1] + wid * 2048;
                #pragma unroll
                for (int i = 0; i < 4; i++)
                    stage16(g + i * 512, l + i * 512);
            }
            const __bf16* kl = (const __bf16*)k_lds[ch & 1] + klo;
            f32x16 sa, sb, sc, sd;
            #pragma unroll
            for (int i = 0; i < 16; i++) { sa[i] = 0.f; sb[i] = 0.f; sc[i] = 0.f; sd[i] = 0.f; }
            __builtin_amdgcn_s_setprio(1);
            #pragma unroll
            for (int i = 0; i < 4; i++) {    // four independent 4-deep chains
                bf16x8 ka = *(const bf16x8*)(kl + i * 512);
                bf16x8 kb = *(const bf16x8*)(kl + (i + 4) * 512);
                bf16x8 kc = *(const bf16x8*)(kl + (i + 8) * 512);
                bf16x8 kd = *(const bf16x8*)(kl + (i + 12) * 512);
                sa = __builtin_amdgcn_mfma_f32_32x32x16_bf16(ka, qf[i], sa, 0, 0, 0);
                sb = __builtin_amdgcn_mfma_f32_32x32x16_bf16(kb, qf[i + 4], sb, 0, 0, 0);
                sc = __builtin_amdgcn_mfma_f32_32x32x16_bf16(kc, qf[i + 8], sc, 0, 0, 0);
                sd = __builtin_amdgcn_mfma_f32_32x32x16_bf16(kd, qf[i + 12], sd, 0, 0, 0);
            }
            __builtin_amdgcn_s_setprio(0);
            char* pbuf = (char*)p_lds[ch & 1];
            #pragma unroll
            for (int gI = 0; gI < 4; gI++) {
                bf16x4 pw;
                #pragma unroll
                for (int j = 0; j < 4; j++) {
                    float p = __expf(sa[gI * 4 + j] + sb[gI * 4 + j]
                                     + sc[gI * 4 + j] + sd[gI * 4 + j]);
                    l_acc += p;
                    pw[j] = (__bf16)p;
                }
                int off = prow * 128 + kt * 64 + 16 * gI + 8 * q2;
                *(bf16x4*)(pbuf + (off ^ swz)) = pw;
            }
        }
        // l row sums -> global scratch (committed by the barrier's vmcnt drain)
        l_acc += __shfl_down(l_acc, 32);
        if (lane < 32) lt[kt * 64 + rt * 32 + lane] = l_acc;
        __syncthreads();                     // pairs with consumer tail barrier
    } else {
        // ================= CONSUMER =================
        int cw = wid - 4;                    // owns chans [cw*64, +64)
        const __bf16* vbase = v + (size_t)b * BSTR + (size_t)split * 524288
                              + (size_t)q2 * 2048 + n31 * 8;
        f32x16 o_acc[2][2];                  // [ct][rt]
        #pragma unroll
        for (int ct = 0; ct < 2; ct++)
            #pragma unroll
            for (int rt = 0; rt < 2; rt++)
                #pragma unroll
                for (int i = 0; i < 16; i++) o_acc[ct][rt][i] = 0.f;

        bf16x8 vf[2][4];                     // V for the NEXT-consumed chunk;
                                             // lives across the barrier.
        for (int ch = 0; ch < NCH; ch++) {
            __syncthreads();
            if (ch < NCH - 1) {              // stage K[ch+1] share
                const __bf16* g = kgbase + (size_t)(ch + 1) * 16384;
                __bf16* l = (__bf16*)k_lds[(ch + 1) & 1] + wid * 2048;
                #pragma unroll
                for (int i = 0; i < 4; i++)
                    stage16(g + i * 512, l + i * 512);
            }
            if (ch > 0) {
                int cc = ch - 1;
                const char* pbuf = (const char*)p_lds[cc & 1];
                __builtin_amdgcn_s_setprio(1);
                #pragma unroll
                for (int rt = 0; rt < 2; rt++) {
                    int prow = rt * 32 + n31;
                    int swz  = (prow & 7) << 4;
                    int pbs  = prow * 128 + q2 * 16;
                    #pragma unroll
                    for (int ks4 = 0; ks4 < 4; ks4++) {
                        bf16x8 pf = *(const bf16x8*)(pbuf + ((pbs + ks4 * 32) ^ swz));
                        o_acc[0][rt] = __builtin_amdgcn_mfma_f32_32x32x16_bf16(
                            vf[0][ks4], pf, o_acc[0][rt], 0, 0, 0);
                        o_acc[1][rt] = __builtin_amdgcn_mfma_f32_32x32x16_bf16(
                            vf[1][ks4], pf, o_acc[1][rt], 0, 0, 0);
                    }
                }
                __builtin_amdgcn_s_setprio(0);
            }
            // Prefetch V for chunk ch (consumed in iteration ch+1 / tail);
            // issued before the barrier so its latency drains there.
            #pragma unroll
            for (int ct = 0; ct < 2; ct++)
                #pragma unroll
                for (int ks4 = 0; ks4 < 4; ks4++) {
                    size_t off = (size_t)(ch * 2 + (ks4 >> 1)) * 8192
                               + (size_t)(ks4 & 1) * 4096 + (cw * 2 + ct) * 256;
                    vf[ct][ks4] = *(const bf16x8*)(vbase + off);
                }
            asm volatile("" ::: "memory");   // don't sink loads past barrier
        }
        __syncthreads();                     // pairs with producer tail barrier
        // l for rows n31 and 32+n31 (kt slots summed); L2-hit, hidden by tail.
        float lA = lt[n31] + lt[64 + n31];
        float lB = lt[32 + n31] + lt[64 + 32 + n31];
        {   // tail: consume chunk 31 from p_lds[1] with already-loaded vf
            const char* pbuf = (const char*)p_lds[1];
            __builtin_amdgcn_s_setprio(1);
            #pragma unroll
            for (int rt = 0; rt < 2; rt++) {
                int prow = rt * 32 + n31;
                int swz  = (prow & 7) << 4;
                int pbs  = prow * 128 + q2 * 16;
                #pragma unroll
                for (int ks4 = 0; ks4 < 4; ks4++) {
                    bf16x8 pf = *(const bf16x8*)(pbuf + ((pbs + ks4 * 32) ^ swz));
                    o_acc[0][rt] = __builtin_amdgcn_mfma_f32_32x32x16_bf16(
                        vf[0][ks4], pf, o_acc[0][rt], 0, 0, 0);
                    o_acc[1][rt] = __builtin_amdgcn_mfma_f32_32x32x16_bf16(
                        vf[1][ks4], pf, o_acc[1][rt], 0, 0, 0);
                }
            }
            __builtin_amdgcn_s_setprio(0);
        }
        // lpart plane for proj (one consumer wave).
        if (wid == 4 && lane < 32) {
            float* lp = lpart + ((size_t)split * B_ + b) * N_ + n0;
            lp[n31]      = lA;
            lp[32 + n31] = lB;
        }
        // Normalize by split-local l, store bf16 partials (plane per split).
        float inv0 = 1.0f / lA;
        float inv1 = 1.0f / lB;
        __bf16* aop = aob + (size_t)split * PLANE;
        #pragma unroll
        for (int ct = 0; ct < 2; ct++)
            #pragma unroll
            for (int rt = 0; rt < 2; rt++) {
                float inv = rt ? inv1 : inv0;
                #pragma unroll
                for (int g = 0; g < 4; g++) {
                    bf16x4 st;
                    #pragma unroll
                    for (int j = 0; j < 4; j++)
                        st[j] = (__bf16)(o_acc[ct][rt][g * 4 + j] * inv);
                    size_t idx = ((((((size_t)(b * 64 + qt) * 4 + cw) * 2 + ct) * 2 + rt)
                                   * 4 + g) * 2 + q2) * 128 + n31 * 4;
                    *(bf16x4*)(aop + idx) = st;
                }
            }
    }
}

// ---------------------------------------------------------------------------
// Kernel 4 (verbatim R15, ran): out projection, bf16 W2, grid 512,
// 2 tiles/block.
// ---------------------------------------------------------------------------
__global__ __launch_bounds__(256) void proj_kernel(const __bf16* __restrict__ aob,
                                                   const float* __restrict__ lpart,
                                                   const __bf16* __restrict__ W2b,
                                                   const float* __restrict__ bias,
                                                   const float* __restrict__ x,
                                                   float* __restrict__ out) {
    int bid = blockIdx.x;                      // 0..511
    int b   = (bid & 7) >> 1;
    int u   = ((bid >> 3) << 1) | (bid & 1);   // 0..127
    int ot  = u >> 6;                          // 0..1
    int tp  = u & 63;                          // 0..63 (tile pair)
    int tid = threadIdx.x, wv = tid >> 6, lane = tid & 63;
    int n31 = lane & 31, q2 = lane >> 5;
    int B0 = ot * 128 + wv * 32;
    const size_t BN = (size_t)B_ * N_;
    const size_t PLANE = (size_t)B_ * C_ * N_;

    bf16x8 wf[16];
    const __bf16* wp = W2b + (size_t)(B0 + n31) * C_;
    #pragma unroll
    for (int ks = 0; ks < 16; ks++)
        wf[ks] = *(const bf16x8*)(wp + ks * 16 + q2 * 8);
    float bv[16];
    #pragma unroll
    for (int r = 0; r < 16; r++) bv[r] = bias[B0 + (r & 3) + 8 * (r >> 2) + 4 * q2];

    for (int t = 0; t < 2; t++) {
        int nt = tp * 2 + t;                  // 32-row tile, 0..127
        int qt = nt >> 1, rtile = nt & 1;
        int n = nt * 32 + n31;
        size_t ln = (size_t)b * N_ + n;
        float l0v = lpart[ln];
        float l1v = lpart[BN + ln];
        float invt = 1.0f / (l0v + l1v);
        float w0 = l0v * invt, w1 = l1v * invt;

        bf16x8 xf[16];
        #pragma unroll
        for (int ks = 0; ks < 16; ks++) {
            int oct = ks * 2 + q2;            // chan octet 0..31
            int cw = oct >> 3, ct = (oct >> 2) & 1, ga = oct & 3;
            size_t base = ((((((size_t)(b * 64 + qt) * 4 + cw) * 2 + ct) * 2 + rtile)
                            * 4 + ga) * 2) * 128 + n31 * 4;
            bf16x4 a0 = *(const bf16x4*)(aob + base);
            bf16x4 b0 = *(const bf16x4*)(aob + base + 128);
            bf16x4 a1 = *(const bf16x4*)(aob + PLANE + base);
            bf16x4 b1 = *(const bf16x4*)(aob + PLANE + base + 128);
            bf16x8 f;
            #pragma unroll
            for (int j = 0; j < 4; j++) {
                f[j]     = (__bf16)(w0 * (float)a0[j] + w1 * (float)a1[j]);
                f[4 + j] = (__bf16)(w0 * (float)b0[j] + w1 * (float)b1[j]);
            }
            xf[ks] = f;
        }

        f32x16 acc;
        #pragma unroll
        for (int i = 0; i < 16; i++) acc[i] = 0.f;
        #pragma unroll
        for (int ks = 0; ks < 16; ks++)
            acc = __builtin_amdgcn_mfma_f32_32x32x16_bf16(wf[ks], xf[ks], acc, 0, 0, 0);

        #pragma unroll
        for (int r = 0; r < 16; r++) {
            int o = B0 + (r & 3) + 8 * (r >> 2) + 4 * q2;
            size_t idx = ((size_t)(b * C_ + o)) * N_ + nt * 32 + n31;
            out[idx] = acc[r] + bv[r] + x[idx];
        }
    }
}

// ---------------------------------------------------------------------------
extern "C" void kernel_launch(void* const* d_in, const int* in_sizes, int n_in,
                              void* d_out, int out_size, void* d_ws, size_t ws_size,
                              hipStream_t stream) {
    const float* x     = (const float*)d_in[0];
    const float* gn_w  = (const float*)d_in[1];
    const float* gn_b  = (const float*)d_in[2];
    const float* qkv_w = (const float*)d_in[3];
    const float* qkv_b = (const float*)d_in[4];
    const float* out_w = (const float*)d_in[5];
    const float* out_b = (const float*)d_in[6];
    float* out = (float*)d_out;

    const size_t SZ = (size_t)B_ * C_ * N_;       // 4,194,304 elements
    char* base = (char*)d_ws;
    __bf16* aob = (__bf16*)base;                  // 2 bf16 planes = 16.8 MB
    __bf16* xnb = (__bf16*)base;                  // aliases aob (dead by attn)
    __bf16* qb  = (__bf16*)(base + 2 * SZ * 4);   // 8.39 MB each
    __bf16* kb  = qb + SZ;
    __bf16* vb  = kb + SZ;
    float*  lpart = (float*)(base + 2 * SZ * 4 + 3 * SZ * 2);  // [2][B][N] fp32
    float*  part  = lpart + 2 * (size_t)B_ * N_;  // [640][2] GN partials
    float*  ltmp  = part + 1536;                  // [512][128] l scratch, 256 KB
    __bf16* wqb   = (__bf16*)(ltmp + 512 * 128);  // qkv_w bf16, 384 KB
    __bf16* wob   = wqb + QKVW_ELEMS;             // out_w bf16, 128 KB

    gn_stats_kernel<<<dim3(640), 256, 0, stream>>>(x, part, qkv_w, out_w, wqb, wob);
    gn_apply_kernel<<<dim3(512), 256, 0, stream>>>(x, gn_w, gn_b, part, xnb);
    qkv_kernel<<<dim3(768), 256, 0, stream>>>(xnb, qkv_w, qkv_b, qb, kb, vb);
    attn_kernel<<<dim3(512), 512, 0, stream>>>(qb, kb, vb, aob, lpart, ltmp);
    proj_kernel<<<dim3(512), 256, 0, stream>>>(aob, lpart, wob, out_b, x, out);
}

// Round 17
// 197.700 us; speedup vs baseline: 1.0949x; 1.0949x over previous
//
#include <hip/hip_runtime.h>
#include <math.h>

#define B_   4
#define C_   256
#define G_   32
#define CPG  8                 // channels per group
#define N_   4096              // H*W
#define NPG  (CPG * N_)        // 32768 elements per group
#define EPS  1e-5f
#define SCALE 0.0625f          // C^-0.5 = 1/16
#define NCH  32                // key chunks of 64 per (split) half
#define QKVW_ELEMS 196608      // 3C x C
#define OUTW_ELEMS 65536       // C x C

typedef __attribute__((ext_vector_type(8)))  __bf16 bf16x8;
typedef __attribute__((ext_vector_type(4)))  __bf16 bf16x4;
typedef __attribute__((ext_vector_type(16))) float  f32x16;

__device__ __forceinline__ void stage16(const __bf16* g, __bf16* l) {
    __builtin_amdgcn_global_load_lds(
        (const __attribute__((address_space(1))) unsigned int*)g,
        (__attribute__((address_space(3))) unsigned int*)l, 16, 0, 0);
}

// ---------------------------------------------------------------------------
// Kernel 1a: GroupNorm partial sums (blocks 0..511) + weight bf16
// pre-conversion side-job (blocks 512..639). Verbatim R15 (ran).
// ---------------------------------------------------------------------------
__global__ __launch_bounds__(256) void gn_stats_kernel(const float* __restrict__ x,
                                                       float* __restrict__ part,
                                                       const float* __restrict__ qw,
                                                       const float* __restrict__ ow,
                                                       __bf16* __restrict__ wqb,
                                                       __bf16* __restrict__ wob) {
    int bid = blockIdx.x;
    if (bid >= 512) {
        int et = (bid - 512) * 256 + threadIdx.x;   // 0..32767
        int e8 = et * 8;
        const float* src;
        __bf16* dst;
        if (e8 < QKVW_ELEMS) { src = qw + e8; dst = wqb + e8; }
        else { src = ow + (e8 - QKVW_ELEMS); dst = wob + (e8 - QKVW_ELEMS); }
        float4 t0 = *(const float4*)src;
        float4 t1 = *(const float4*)(src + 4);
        bf16x8 f;
        f[0] = (__bf16)t0.x; f[1] = (__bf16)t0.y; f[2] = (__bf16)t0.z; f[3] = (__bf16)t0.w;
        f[4] = (__bf16)t1.x; f[5] = (__bf16)t1.y; f[6] = (__bf16)t1.z; f[7] = (__bf16)t1.w;
        *(bf16x8*)dst = f;
        return;
    }
    int bg = bid >> 2, seg = bid & 3;
    const float4* xp4 = (const float4*)(x + (size_t)bg * NPG) + seg * 2048;
    int tid = threadIdx.x;

    float s = 0.f, ss = 0.f;
    for (int i = tid; i < 2048; i += 256) {
        float4 t = xp4[i];
        s  += t.x + t.y + t.z + t.w;
        ss += t.x * t.x + t.y * t.y + t.z * t.z + t.w * t.w;
    }
    #pragma unroll
    for (int off = 32; off; off >>= 1) {
        s  += __shfl_xor(s, off, 64);
        ss += __shfl_xor(ss, off, 64);
    }
    __shared__ float rs[2][4];
    int wave = tid >> 6, lane = tid & 63;
    if (lane == 0) { rs[0][wave] = s; rs[1][wave] = ss; }
    __syncthreads();
    if (tid == 0) {
        part[bid * 2]     = rs[0][0] + rs[0][1] + rs[0][2] + rs[0][3];
        part[bid * 2 + 1] = rs[1][0] + rs[1][1] + rs[1][2] + rs[1][3];
    }
}

// ---------------------------------------------------------------------------
// Kernel 1b: GroupNorm apply, float4-vectorized. Grid 512. Verbatim R15.
// ---------------------------------------------------------------------------
__global__ __launch_bounds__(256) void gn_apply_kernel(const float* __restrict__ x,
                                                       const float* __restrict__ w,
                                                       const float* __restrict__ bia,
                                                       const float* __restrict__ part,
                                                       __bf16* __restrict__ xnb) {
    int bid = blockIdx.x;                      // 0..511
    int b   = (bid & 7) >> 1;
    int u   = ((bid >> 3) << 1) | (bid & 1);   // 0..127
    int g   = u >> 2;
    int seg = u & 3;
    int bg  = b * 32 + g;
    float s  = part[(bg * 4 + 0) * 2] + part[(bg * 4 + 1) * 2]
             + part[(bg * 4 + 2) * 2] + part[(bg * 4 + 3) * 2];
    float ss = part[(bg * 4 + 0) * 2 + 1] + part[(bg * 4 + 1) * 2 + 1]
             + part[(bg * 4 + 2) * 2 + 1] + part[(bg * 4 + 3) * 2 + 1];
    float mean = s / (float)NPG;
    float var  = ss / (float)NPG - mean * mean;
    float rstd = rsqrtf(var + EPS);

    const float* xp = x + (size_t)bg * NPG;
    int n0 = seg * 1024 + threadIdx.x * 4;

    float4 t[8];
    #pragma unroll
    for (int cc = 0; cc < 8; cc++)
        t[cc] = *(const float4*)(xp + (size_t)cc * N_ + n0);

    float sc[8], sh[8];
    #pragma unroll
    for (int cc = 0; cc < 8; cc++) {
        sc[cc] = rstd * w[g * CPG + cc];
        sh[cc] = bia[g * CPG + cc] - mean * sc[cc];
    }

    size_t base = ((((size_t)(b * 128 + (n0 >> 5)) * 16 + (g >> 1)) * 2 + (g & 1))
                   * 32 + (n0 & 31)) * 8;
    #pragma unroll
    for (int j = 0; j < 4; j++) {
        bf16x8 pk;
        #pragma unroll
        for (int cc = 0; cc < 8; cc++) {
            float tv = ((const float*)&t[cc])[j];
            pk[cc] = (__bf16)(tv * sc[cc] + sh[cc]);
        }
        *(bf16x8*)(xnb + base + j * 8) = pk;
    }
}

// ---------------------------------------------------------------------------
// Kernel 2: QKV projection (fp32 W), LDS double-buffered x-tiles, grid 768.
// Verbatim R15.
// ---------------------------------------------------------------------------
__global__ __launch_bounds__(256) void qkv_kernel(const __bf16* __restrict__ xnb,
                                                  const float* __restrict__ W,
                                                  const float* __restrict__ bias,
                                                  __bf16* __restrict__ q,
                                                  __bf16* __restrict__ k,
                                                  __bf16* __restrict__ v) {
    __shared__ __align__(16) __bf16 x_lds[2][8192];   // 2 x 16 KB
    int bid = blockIdx.x;
    int b   = (bid & 7) >> 1;
    int t2  = ((bid >> 3) << 1) | (bid & 1);   // 0..191
    int ot  = t2 >> 5;
    int nc  = t2 & 31;
    int tid = threadIdx.x, wv = tid >> 6, lane = tid & 63;
    int n31 = lane & 31, q2 = lane >> 5;
    int B0 = ot * 128 + wv * 32;

    bf16x8 wf[16];
    const float* wp = W + (size_t)(B0 + n31) * C_;
    #pragma unroll
    for (int ks = 0; ks < 16; ks++) {
        float4 t0 = *(const float4*)(wp + ks * 16 + q2 * 8);
        float4 t1 = *(const float4*)(wp + ks * 16 + q2 * 8 + 4);
        bf16x8 f;
        f[0] = (__bf16)t0.x; f[1] = (__bf16)t0.y; f[2] = (__bf16)t0.z; f[3] = (__bf16)t0.w;
        f[4] = (__bf16)t1.x; f[5] = (__bf16)t1.y; f[6] = (__bf16)t1.z; f[7] = (__bf16)t1.w;
        wf[ks] = f;
    }

    float bv[16], bvv = 0.f;
    if (ot < 4) {
        #pragma unroll
        for (int gI = 0; gI < 4; gI++)
            #pragma unroll
            for (int j = 0; j < 4; j++)
                bv[gI * 4 + j] = bias[B0 + gI * 8 + 4 * q2 + j];
    } else {
        bvv = bias[B0 + n31];
    }

    const __bf16* xb = xnb + (size_t)b * 128 * 8192;
    const __bf16* xgs = xb + (size_t)(nc * 4) * 8192 + wv * 2048 + lane * 8;

    {   // prologue: stage tile 0
        __bf16* l = (__bf16*)x_lds[0] + wv * 2048;
        #pragma unroll
        for (int i = 0; i < 4; i++)
            stage16(xgs + i * 512, l + i * 512);
    }

    for (int t = 0; t < 4; t++) {
        __syncthreads();                      // tile t staged
        if (t < 3) {                          // stage tile t+1
            const __bf16* g_ = xgs + (size_t)(t + 1) * 8192;
            __bf16* l = (__bf16*)x_lds[(t + 1) & 1] + wv * 2048;
            #pragma unroll
            for (int i = 0; i < 4; i++)
                stage16(g_ + i * 512, l + i * 512);
        }
        int nt = nc * 4 + t;
        const __bf16* xl = (const __bf16*)x_lds[t & 1] + q2 * 256 + n31 * 8;
        bf16x8 xf[16];
        #pragma unroll
        for (int ks = 0; ks < 16; ks++) xf[ks] = *(const bf16x8*)(xl + ks * 512);

        f32x16 acc;
        #pragma unroll
        for (int i = 0; i < 16; i++) acc[i] = 0.f;
        if (ot < 4) {
            #pragma unroll
            for (int ks = 0; ks < 16; ks++)
                acc = __builtin_amdgcn_mfma_f32_32x32x16_bf16(wf[ks], xf[ks], acc, 0, 0, 0);
        } else {
            #pragma unroll
            for (int ks = 0; ks < 16; ks++)
                acc = __builtin_amdgcn_mfma_f32_32x32x16_bf16(xf[ks], wf[ks], acc, 0, 0, 0);
        }

        if (ot < 4) {
            int ocb = (ot < 2) ? B0 : (B0 - 256);
            __bf16* dst = (ot < 2) ? q : k;
            bool isq = (ot < 2);
            #pragma unroll
            for (int gI = 0; gI < 4; gI++) {
                bf16x4 pk;
                #pragma unroll
                for (int j = 0; j < 4; j++) {
                    float y = acc[gI * 4 + j] + bv[gI * 4 + j];
                    if (isq) y *= SCALE;
                    pk[j] = (__bf16)y;
                }
                size_t idx = ((((size_t)(b * 128 + nt) * 16 + ((ocb >> 4) + (gI >> 1))) * 2
                               + (gI & 1)) * 32 + n31) * 8 + 4 * q2;
                *(bf16x4*)(dst + idx) = pk;
            }
        } else {
            int ocb = B0 - 512;
            #pragma unroll
            for (int gI = 0; gI < 4; gI++) {
                bf16x4 pk;
                #pragma unroll
                for (int j = 0; j < 4; j++)
                    pk[j] = (__bf16)(acc[gI * 4 + j] + bvv);
                size_t idx = (((((size_t)(b * 128 + nt) * 2 + (gI >> 1)) * 2 + (gI & 1)) * 8
                               + (ocb >> 5)) * 32 + n31) * 8 + 4 * q2;
                *(bf16x4*)(v + idx) = pk;
            }
        }
    }
}

// ---------------------------------------------------------------------------
// Kernel 3: producer/consumer attention, verbatim R15 (ran, best):
// async-K LDS dbuf, two 8-deep producer chains, ct-reuse consumer with
// cross-barrier register-resident V prefetch, l via global scratch,
// normalized bf16 output planes. LDS 81920, 2 blocks/CU.
// ---------------------------------------------------------------------------
__global__ __launch_bounds__(512, 4) void attn_kernel(const __bf16* __restrict__ q,
                                                      const __bf16* __restrict__ k,
                                                      const __bf16* __restrict__ v,
                                                      __bf16* __restrict__ aob,
                                                      float* __restrict__ lpart,
                                                      float* __restrict__ ltmp) {
    __shared__ __align__(16) __bf16 k_lds[2][16384];   // 2 x 32 KB double buffer
    __shared__ __align__(16) __bf16 p_lds[2][64 * 64]; // 2 x 8 KB, XOR-swizzled

    int bid   = blockIdx.x;
    int xcd   = bid & 7;
    int b     = xcd >> 1;
    int split = xcd & 1;
    int qt    = bid >> 3;                    // 0..63, 64-row q tile
    int n0    = qt * 64;

    int tid = threadIdx.x;
    int wid = tid >> 6, lane = tid & 63;
    int n31 = lane & 31, q2 = lane >> 5;

    const size_t BSTR = (size_t)N_ * C_;
    const size_t PLANE = (size_t)B_ * C_ * N_;   // elements per split plane
    float* lt = ltmp + (size_t)bid * 128;        // [kt][64] per-block scratch
    const __bf16* kgbase = k + (size_t)(b * 128 + split * 64) * 8192
                           + wid * 2048 + lane * 8;

    // prologue: stage chunk 0 into buf 0 (each wave: 4 x 1 KB segments)
    {
        __bf16* l = (__bf16*)k_lds[0] + wid * 2048;
        #pragma unroll
        for (int i = 0; i < 4; i++)
            stage16(kgbase + i * 512, l + i * 512);
    }

    if (wid < 4) {
        // ================= PRODUCER =================
        int kt = wid & 1;                    // 32-key slice within chunk
        int rt = wid >> 1;                   // 32-row tile within 64 rows
        const __bf16* qg = q + (size_t)(b * 128 + qt * 2 + rt) * 8192
                           + q2 * 256 + n31 * 8;
        bf16x8 qf[16];
        #pragma unroll
        for (int ks = 0; ks < 16; ks++) qf[ks] = *(const bf16x8*)(qg + ks * 512);

        float l_acc = 0.f;
        int prow = rt * 32 + n31;
        int swz  = (prow & 7) << 4;
        int klo  = kt * 8192 + q2 * 256 + n31 * 8;

        for (int ch = 0; ch < NCH; ch++) {
            __syncthreads();                 // K[ch] staged, P[(ch-1)] consumed
            if (ch < NCH - 1) {              // stage K[ch+1] into other buffer
                const __bf16* g = kgbase + (size_t)(ch + 1) * 16384;
                __bf16* l = (__bf16*)k_lds[(ch + 1) & 1] + wid * 2048;
                #pragma unroll
                for (int i = 0; i < 4; i++)
                    stage16(g + i * 512, l + i * 512);
            }
            const __bf16* kl = (const __bf16*)k_lds[ch & 1] + klo;
            f32x16 sa, sb;
            #pragma unroll
            for (int i = 0; i < 16; i++) { sa[i] = 0.f; sb[i] = 0.f; }
            __builtin_amdgcn_s_setprio(1);
            #pragma unroll
            for (int i = 0; i < 8; i++) {    // two independent 8-deep chains
                bf16x8 ka = *(const bf16x8*)(kl + i * 512);
                bf16x8 kb = *(const bf16x8*)(kl + (i + 8) * 512);
                sa = __builtin_amdgcn_mfma_f32_32x32x16_bf16(ka, qf[i], sa, 0, 0, 0);
                sb = __builtin_amdgcn_mfma_f32_32x32x16_bf16(kb, qf[i + 8], sb, 0, 0, 0);
            }
            __builtin_amdgcn_s_setprio(0);
            char* pbuf = (char*)p_lds[ch & 1];
            #pragma unroll
            for (int gI = 0; gI < 4; gI++) {
                bf16x4 pw;
                #pragma unroll
                for (int j = 0; j < 4; j++) {
                    float p = __expf(sa[gI * 4 + j] + sb[gI * 4 + j]);
                    l_acc += p;
                    pw[j] = (__bf16)p;
                }
                int off = prow * 128 + kt * 64 + 16 * gI + 8 * q2;
                *(bf16x4*)(pbuf + (off ^ swz)) = pw;
            }
        }
        // l row sums -> global scratch (committed by the barrier's vmcnt drain)
        l_acc += __shfl_down(l_acc, 32);
        if (lane < 32) lt[kt * 64 + rt * 32 + lane] = l_acc;
        __syncthreads();                     // pairs with consumer tail barrier
    } else {
        // ================= CONSUMER =================
        int cw = wid - 4;                    // owns chans [cw*64, +64)
        const __bf16* vbase = v + (size_t)b * BSTR + (size_t)split * 524288
                              + (size_t)q2 * 2048 + n31 * 8;
        f32x16 o_acc[2][2];                  // [ct][rt]
        #pragma unroll
        for (int ct = 0; ct < 2; ct++)
            #pragma unroll
            for (int rt = 0; rt < 2; rt++)
                #pragma unroll
                for (int i = 0; i < 16; i++) o_acc[ct][rt][i] = 0.f;

        bf16x8 vf[2][4];                     // V for the NEXT-consumed chunk;
                                             // lives across the barrier.
        for (int ch = 0; ch < NCH; ch++) {
            __syncthreads();
            if (ch < NCH - 1) {              // stage K[ch+1] share
                const __bf16* g = kgbase + (size_t)(ch + 1) * 16384;
                __bf16* l = (__bf16*)k_lds[(ch + 1) & 1] + wid * 2048;
                #pragma unroll
                for (int i = 0; i < 4; i++)
                    stage16(g + i * 512, l + i * 512);
            }
            if (ch > 0) {
                int cc = ch - 1;
                const char* pbuf = (const char*)p_lds[cc & 1];
                __builtin_amdgcn_s_setprio(1);
                #pragma unroll
                for (int rt = 0; rt < 2; rt++) {
                    int prow = rt * 32 + n31;
                    int swz  = (prow & 7) << 4;
                    int pbs  = prow * 128 + q2 * 16;
                    #pragma unroll
                    for (int ks4 = 0; ks4 < 4; ks4++) {
                        bf16x8 pf = *(const bf16x8*)(pbuf + ((pbs + ks4 * 32) ^ swz));
                        o_acc[0][rt] = __builtin_amdgcn_mfma_f32_32x32x16_bf16(
                            vf[0][ks4], pf, o_acc[0][rt], 0, 0, 0);
                        o_acc[1][rt] = __builtin_amdgcn_mfma_f32_32x32x16_bf16(
                            vf[1][ks4], pf, o_acc[1][rt], 0, 0, 0);
                    }
                }
                __builtin_amdgcn_s_setprio(0);
            }
            // Prefetch V for chunk ch (consumed in iteration ch+1 / tail);
            // issued before the barrier so its latency drains there.
            #pragma unroll
            for (int ct = 0; ct < 2; ct++)
                #pragma unroll
                for (int ks4 = 0; ks4 < 4; ks4++) {
                    size_t off = (size_t)(ch * 2 + (ks4 >> 1)) * 8192
                               + (size_t)(ks4 & 1) * 4096 + (cw * 2 + ct) * 256;
                    vf[ct][ks4] = *(const bf16x8*)(vbase + off);
                }
            asm volatile("" ::: "memory");   // don't sink loads past barrier
        }
        __syncthreads();                     // pairs with producer tail barrier
        // l for rows n31 and 32+n31 (kt slots summed); L2-hit, hidden by tail.
        float lA = lt[n31] + lt[64 + n31];
        float lB = lt[32 + n31] + lt[64 + 32 + n31];
        {   // tail: consume chunk 31 from p_lds[1] with already-loaded vf
            const char* pbuf = (const char*)p_lds[1];
            __builtin_amdgcn_s_setprio(1);
            #pragma unroll
            for (int rt = 0; rt < 2; rt++) {
                int prow = rt * 32 + n31;
                int swz  = (prow & 7) << 4;
                int pbs  = prow * 128 + q2 * 16;
                #pragma unroll
                for (int ks4 = 0; ks4 < 4; ks4++) {
                    bf16x8 pf = *(const bf16x8*)(pbuf + ((pbs + ks4 * 32) ^ swz));
                    o_acc[0][rt] = __builtin_amdgcn_mfma_f32_32x32x16_bf16(
                        vf[0][ks4], pf, o_acc[0][rt], 0, 0, 0);
                    o_acc[1][rt] = __builtin_amdgcn_mfma_f32_32x32x16_bf16(
                        vf[1][ks4], pf, o_acc[1][rt], 0, 0, 0);
                }
            }
            __builtin_amdgcn_s_setprio(0);
        }
        // lpart plane for proj (one consumer wave).
        if (wid == 4 && lane < 32) {
            float* lp = lpart + ((size_t)split * B_ + b) * N_ + n0;
            lp[n31]      = lA;
            lp[32 + n31] = lB;
        }
        // Normalize by split-local l, store bf16 partials (plane per split).
        float inv0 = 1.0f / lA;
        float inv1 = 1.0f / lB;
        __bf16* aop = aob + (size_t)split * PLANE;
        #pragma unroll
        for (int ct = 0; ct < 2; ct++)
            #pragma unroll
            for (int rt = 0; rt < 2; rt++) {
                float inv = rt ? inv1 : inv0;
                #pragma unroll
                for (int g = 0; g < 4; g++) {
                    bf16x4 st;
                    #pragma unroll
                    for (int j = 0; j < 4; j++)
                        st[j] = (__bf16)(o_acc[ct][rt][g * 4 + j] * inv);
                    size_t idx = ((((((size_t)(b * 64 + qt) * 4 + cw) * 2 + ct) * 2 + rt)
                                   * 4 + g) * 2 + q2) * 128 + n31 * 4;
                    *(bf16x4*)(aop + idx) = st;
                }
            }
    }
}

// ---------------------------------------------------------------------------
// Kernel 4: out projection, bf16 W2, grid 512, 2 tiles/block. Verbatim R15.
// ---------------------------------------------------------------------------
__global__ __launch_bounds__(256) void proj_kernel(const __bf16* __restrict__ aob,
                                                   const float* __restrict__ lpart,
                                                   const __bf16* __restrict__ W2b,
                                                   const float* __restrict__ bias,
                                                   const float* __restrict__ x,
                                                   float* __restrict__ out) {
    int bid = blockIdx.x;                      // 0..511
    int b   = (bid & 7) >> 1;
    int u   = ((bid >> 3) << 1) | (bid & 1);   // 0..127
    int ot  = u >> 6;                          // 0..1
    int tp  = u & 63;                          // 0..63 (tile pair)
    int tid = threadIdx.x, wv = tid >> 6, lane = tid & 63;
    int n31 = lane & 31, q2 = lane >> 5;
    int B0 = ot * 128 + wv * 32;
    const size_t BN = (size_t)B_ * N_;
    const size_t PLANE = (size_t)B_ * C_ * N_;

    bf16x8 wf[16];
    const __bf16* wp = W2b + (size_t)(B0 + n31) * C_;
    #pragma unroll
    for (int ks = 0; ks < 16; ks++)
        wf[ks] = *(const bf16x8*)(wp + ks * 16 + q2 * 8);
    float bv[16];
    #pragma unroll
    for (int r = 0; r < 16; r++) bv[r] = bias[B0 + (r & 3) + 8 * (r >> 2) + 4 * q2];

    for (int t = 0; t < 2; t++) {
        int nt = tp * 2 + t;                  // 32-row tile, 0..127
        int qt = nt >> 1, rtile = nt & 1;
        int n = nt * 32 + n31;
        size_t ln = (size_t)b * N_ + n;
        float l0v = lpart[ln];
        float l1v = lpart[BN + ln];
        float invt = 1.0f / (l0v + l1v);
        float w0 = l0v * invt, w1 = l1v * invt;

        bf16x8 xf[16];
        #pragma unroll
        for (int ks = 0; ks < 16; ks++) {
            int oct = ks * 2 + q2;            // chan octet 0..31
            int cw = oct >> 3, ct = (oct >> 2) & 1, ga = oct & 3;
            size_t base = ((((((size_t)(b * 64 + qt) * 4 + cw) * 2 + ct) * 2 + rtile)
                            * 4 + ga) * 2) * 128 + n31 * 4;
            bf16x4 a0 = *(const bf16x4*)(aob + base);
            bf16x4 b0 = *(const bf16x4*)(aob + base + 128);
            bf16x4 a1 = *(const bf16x4*)(aob + PLANE + base);
            bf16x4 b1 = *(const bf16x4*)(aob + PLANE + base + 128);
            bf16x8 f;
            #pragma unroll
            for (int j = 0; j < 4; j++) {
                f[j]     = (__bf16)(w0 * (float)a0[j] + w1 * (float)a1[j]);
                f[4 + j] = (__bf16)(w0 * (float)b0[j] + w1 * (float)b1[j]);
            }
            xf[ks] = f;
        }

        f32x16 acc;
        #pragma unroll
        for (int i = 0; i < 16; i++) acc[i] = 0.f;
        #pragma unroll
        for (int ks = 0; ks < 16; ks++)
            acc = __builtin_amdgcn_mfma_f32_32x32x16_bf16(wf[ks], xf[ks], acc, 0, 0, 0);

        #pragma unroll
        for (int r = 0; r < 16; r++) {
            int o = B0 + (r & 3) + 8 * (r >> 2) + 4 * q2;
            size_t idx = ((size_t)(b * C_ + o)) * N_ + nt * 32 + n31;
            out[idx] = acc[r] + bv[r] + x[idx];
        }
    }
}

// ---------------------------------------------------------------------------
extern "C" void kernel_launch(void* const* d_in, const int* in_sizes, int n_in,
                              void* d_out, int out_size, void* d_ws, size_t ws_size,
                              hipStream_t stream) {
    const float* x     = (const float*)d_in[0];
    const float* gn_w  = (const float*)d_in[1];
    const float* gn_b  = (const float*)d_in[2];
    const float* qkv_w = (const float*)d_in[3];
    const float* qkv_b = (const float*)d_in[4];
    const float* out_w = (const float*)d_in[5];
    const float* out_b = (const float*)d_in[6];
    float* out = (float*)d_out;

    const size_t SZ = (size_t)B_ * C_ * N_;       // 4,194,304 elements
    char* base = (char*)d_ws;
    __bf16* aob = (__bf16*)base;                  // 2 bf16 planes = 16.8 MB
    __bf16* xnb = (__bf16*)base;                  // aliases aob (dead by attn)
    __bf16* qb  = (__bf16*)(base + 2 * SZ * 4);   // 8.39 MB each
    __bf16* kb  = qb + SZ;
    __bf16* vb  = kb + SZ;
    float*  lpart = (float*)(base + 2 * SZ * 4 + 3 * SZ * 2);  // [2][B][N] fp32
    float*  part  = lpart + 2 * (size_t)B_ * N_;  // [640][2] GN partials
    float*  ltmp  = part + 1536;                  // [512][128] l scratch, 256 KB
    __bf16* wqb   = (__bf16*)(ltmp + 512 * 128);  // qkv_w bf16, 384 KB
    __bf16* wob   = wqb + QKVW_ELEMS;             // out_w bf16, 128 KB

    gn_stats_kernel<<<dim3(640), 256, 0, stream>>>(x, part, qkv_w, out_w, wqb, wob);
    gn_apply_kernel<<<dim3(512), 256, 0, stream>>>(x, gn_w, gn_b, part, xnb);
    qkv_kernel<<<dim3(768), 256, 0, stream>>>(xnb, qkv_w, qkv_b, qb, kb, vb);
    attn_kernel<<<dim3(512), 512, 0, stream>>>(qb, kb, vb, aob, lpart, ltmp);
    proj_kernel<<<dim3(512), 256, 0, stream>>>(aob, lpart, wob, out_b, x, out);
}